// Round 9
// baseline (266.666 us; speedup 1.0000x reference)
//
#include <hip/hip_runtime.h>
#include <math.h>

// Problem constants (fixed by reference)
#define NR 2048
#define MC 131072
#define DIM 64
#define KSEL 11                    // k+1 smallest kept per row
#define PPART 64                   // column partitions
#define PART_COLS (MC / PPART)     // 2048 cols per partition
#define CHUNK 128                  // cols per LDS chunk
#define NCHUNK (PART_COLS / CHUNK) // 16
#define ROWS_PER_BLOCK 64          // 4 waves x 16 rows
#define QSTR 34                    // queue stride in halves = 17 dwords (odd -> all 32 banks)
#define BSTRIDE 72                 // padded f16 col stride in LDS (144B, 16B-aligned)

typedef _Float16 v8h __attribute__((ext_vector_type(8)));
typedef _Float16 v2h __attribute__((ext_vector_type(2)));
typedef float v4f __attribute__((ext_vector_type(4)));

// ---------------- prep: bnorm/2 (fp32) + buf -> f16 ----------------
__global__ __launch_bounds__(256) void k_prep_b(const float* __restrict__ buf,
                                                _Float16* __restrict__ B16,
                                                float* __restrict__ bnorm) {
  int gid = blockIdx.x * 256 + threadIdx.x;   // 4 threads per buffer row
  int row = gid >> 2, q = gid & 3;
  const float4* src = (const float4*)(buf + (size_t)row * DIM + q * 16);
  float4 f0 = src[0], f1 = src[1], f2 = src[2], f3 = src[3];
  float s = f0.x*f0.x + f0.y*f0.y + f0.z*f0.z + f0.w*f0.w
          + f1.x*f1.x + f1.y*f1.y + f1.z*f1.z + f1.w*f1.w
          + f2.x*f2.x + f2.y*f2.y + f2.z*f2.z + f2.w*f2.w
          + f3.x*f3.x + f3.y*f3.y + f3.z*f3.z + f3.w*f3.w;
  s += __shfl_xor(s, 1);
  s += __shfl_xor(s, 2);
  if (q == 0) bnorm[row] = s * 0.5f;   // s-form: store ||b||^2 / 2
  union { _Float16 h[16]; uint4 u[2]; } o;
  o.h[0]=(_Float16)f0.x; o.h[1]=(_Float16)f0.y; o.h[2]=(_Float16)f0.z; o.h[3]=(_Float16)f0.w;
  o.h[4]=(_Float16)f1.x; o.h[5]=(_Float16)f1.y; o.h[6]=(_Float16)f1.z; o.h[7]=(_Float16)f1.w;
  o.h[8]=(_Float16)f2.x; o.h[9]=(_Float16)f2.y; o.h[10]=(_Float16)f2.z; o.h[11]=(_Float16)f2.w;
  o.h[12]=(_Float16)f3.x; o.h[13]=(_Float16)f3.y; o.h[14]=(_Float16)f3.z; o.h[15]=(_Float16)f3.w;
  uint4* dst = (uint4*)(B16 + (size_t)row * DIM + q * 16);
  dst[0] = o.u[0]; dst[1] = o.u[1];
}

// branchless bubble-insert into sorted-ascending 11-list. Inserting any value
// >= lst[10] (incl. +inf) is a no-op (it bubbles off the end). 22 min/max ops.
__device__ __forceinline__ void bins11(float v, float lst[KSEL]) {
  float t = v;
#pragma unroll
  for (int j = 0; j < KSEL; ++j) {
    float a = fminf(lst[j], t);
    t = fmaxf(lst[j], t);
    lst[j] = a;
  }
}

// ---------------- main: MFMA + group-packed f16 queue + sorted top-11 --------
// D = A(bufcols) x B(xrows): C-layout gives each lane ONE x-row (n = lane&15).
// s-form: t = dot - ||b||^2/2, d2 = xn - 2t; pass <=> t > thrx = (xn-thr)/2.
// Scan handles one acc (4 candidates) as a GROUP: 3 max + 1 cmp + 2 pk-cvt +
// 2 unconditional b32 queue writes + cursor advance on pass (~3 VALU/cand).
// Non-passing members of a written group are genuine d2 values -> safe to
// insert; slots >= qo are guarded at drain. Staging is software-pipelined.
__global__ __launch_bounds__(256) void k_main(const float* __restrict__ x,
                                              const _Float16* __restrict__ B16,
                                              const float* __restrict__ bnorm,
                                              float* __restrict__ cand) {
  __shared__ __align__(16) _Float16 Bs[CHUNK * BSTRIDE];   // 18432 B
  __shared__ float bns[CHUNK];                             //   512 B
  __shared__ __align__(8) _Float16 qmem[4][64 * QSTR];     // 17408 B -> 36352 B

  const int tid = threadIdx.x;
  const int w = tid >> 6, lane = tid & 63;
  const int quad = lane >> 4, l15 = lane & 15;
  const int row = blockIdx.y * ROWS_PER_BLOCK + w * 16 + l15;  // this lane's x-row
  const int pbase = blockIdx.x * PART_COLS;
  unsigned* q2 = (unsigned*)&qmem[w][lane * QSTR];   // dword view, 4B-aligned

  // x fragments (B-operand: B[k = quad*8+j + 32ks][n = l15]) + exact fp32 norm
  v8h bx0, bx1;
  float xn;
  {
    const float* xr = x + (size_t)row * DIM;
    const float4* xp0 = (const float4*)(xr + quad * 8);
    float4 a0 = xp0[0], a1 = xp0[1];
    const float4* xp1 = (const float4*)(xr + 32 + quad * 8);
    float4 c0 = xp1[0], c1 = xp1[1];
    v8h h0, h1;
    h0[0]=(_Float16)a0.x; h0[1]=(_Float16)a0.y; h0[2]=(_Float16)a0.z; h0[3]=(_Float16)a0.w;
    h0[4]=(_Float16)a1.x; h0[5]=(_Float16)a1.y; h0[6]=(_Float16)a1.z; h0[7]=(_Float16)a1.w;
    h1[0]=(_Float16)c0.x; h1[1]=(_Float16)c0.y; h1[2]=(_Float16)c0.z; h1[3]=(_Float16)c0.w;
    h1[4]=(_Float16)c1.x; h1[5]=(_Float16)c1.y; h1[6]=(_Float16)c1.z; h1[7]=(_Float16)c1.w;
    bx0 = h0; bx1 = h1;
    float s = a0.x*a0.x + a0.y*a0.y + a0.z*a0.z + a0.w*a0.w
            + a1.x*a1.x + a1.y*a1.y + a1.z*a1.z + a1.w*a1.w
            + c0.x*c0.x + c0.y*c0.y + c0.z*c0.z + c0.w*c0.w
            + c1.x*c1.x + c1.y*c1.y + c1.z*c1.z + c1.w*c1.w;
    s += __shfl_xor(s, 16);   // each quad holds a disjoint 16 of the 64 k's
    s += __shfl_xor(s, 32);
    xn = s;
  }

  float lst[KSEL];   // sorted ascending; lst[10] = private threshold (d2 space)
#pragma unroll
  for (int i = 0; i < KSEL; ++i) lst[i] = __builtin_inff();
  float thrx = -__builtin_inff();   // t-space threshold: pass <=> t > thrx

  // staging-prefetch registers (chunk c+1 loaded during chunk c's compute)
  const int scol = tid >> 1, shf = tid & 1;   // 2 threads/col, 32 f16 each
  uint4 pv0, pv1, pv2, pv3;
  float pbn;
  {
    const uint4* src = (const uint4*)(B16 + (size_t)(pbase + scol) * DIM + shf * 32);
    pv0 = src[0]; pv1 = src[1]; pv2 = src[2]; pv3 = src[3];
    pbn = bnorm[pbase + (tid & (CHUNK - 1))];
  }

  for (int c = 0; c < NCHUNK; ++c) {
    const int cb = pbase + c * CHUNK;
    __syncthreads();   // Bs free (all waves done with previous chunk's reads)
    {
      uint4* dst = (uint4*)(Bs + scol * BSTRIDE + shf * 32);
      dst[0] = pv0; dst[1] = pv1; dst[2] = pv2; dst[3] = pv3;
      if (tid < CHUNK) bns[tid] = pbn;
    }
    __syncthreads();   // staged

    // issue next chunk's loads now; latency hides behind scan+drain below
    if (c + 1 < NCHUNK) {
      const int nb = cb + CHUNK;
      const uint4* src = (const uint4*)(B16 + (size_t)(nb + scol) * DIM + shf * 32);
      pv0 = src[0]; pv1 = src[1]; pv2 = src[2]; pv3 = src[3];
      pbn = bnorm[nb + (tid & (CHUNK - 1))];
    }

    int qo = 0;        // queue group cursor
#pragma unroll
    for (int mt = 0; mt < 8; ++mt) {
      v8h a0 = *(const v8h*)(Bs + (mt * 16 + l15) * BSTRIDE + quad * 8);
      v8h a1 = *(const v8h*)(Bs + (mt * 16 + l15) * BSTRIDE + 32 + quad * 8);
      v4f acc = (v4f)(0.0f);
      acc = __builtin_amdgcn_mfma_f32_16x16x32_f16(a0, bx0, acc, 0, 0, 0);
      acc = __builtin_amdgcn_mfma_f32_16x16x32_f16(a1, bx1, acc, 0, 0, 0);
      float4 bh = *(const float4*)&bns[mt * 16 + quad * 4];   // ||b||^2 / 2
      float t0 = acc[0] - bh.x;
      float t1 = acc[1] - bh.y;
      float t2 = acc[2] - bh.z;
      float t3 = acc[3] - bh.w;
      float mx = fmaxf(fmaxf(t0, t1), fmaxf(t2, t3));
      v2h pk0; pk0[0] = (_Float16)t0; pk0[1] = (_Float16)t1;
      v2h pk1; pk1[0] = (_Float16)t2; pk1[1] = (_Float16)t3;
      // unconditional write at the group cursor; cursor advances on pass.
      // Failed-group slots are overwritten or guarded off at drain.
      q2[2 * qo]     = __builtin_bit_cast(unsigned, pk0);
      q2[2 * qo + 1] = __builtin_bit_cast(unsigned, pk1);
      qo += (mx > thrx) ? 1 : 0;
    }

    // group drain: 2 b32 reads -> 4 d2 -> guarded min4 -> ballot-gated inserts
    for (int i = 0; __ballot(i < qo); ++i) {
      unsigned u0 = q2[2 * i], u1 = q2[2 * i + 1];
      v2h p0 = __builtin_bit_cast(v2h, u0);
      v2h p1 = __builtin_bit_cast(v2h, u1);
      bool ok = i < qo;
      float v0 = fmaf((float)p0[0], -2.0f, xn);   // d2 = xn - 2t
      float v1 = fmaf((float)p0[1], -2.0f, xn);
      float v2 = fmaf((float)p1[0], -2.0f, xn);
      float v3 = fmaf((float)p1[1], -2.0f, xn);
      v0 = ok ? v0 : __builtin_inff();
      v1 = ok ? v1 : __builtin_inff();
      v2 = ok ? v2 : __builtin_inff();
      v3 = ok ? v3 : __builtin_inff();
      float m = fminf(fminf(v0, v1), fminf(v2, v3));
      if (__ballot(m < lst[KSEL - 1])) {   // any lane improves its list?
        bins11(v0, lst); bins11(v1, lst);  // v >= lst[10] inserts are no-ops
        bins11(v2, lst); bins11(v3, lst);
      }
    }

    // tighten shared threshold: min over the 4 quads holding this row
    float th = fminf(lst[KSEL - 1], __shfl_xor(lst[KSEL - 1], 16));
    th = fminf(th, __shfl_xor(th, 32));
    thrx = (xn - th) * 0.5f;   // t > thrx  <=>  d2 < th   (inf-safe)
  }

  // merge the 4 quads' sorted lists (disjoint col subsets of the same row)
#pragma unroll
  for (int s = 16; s <= 32; s <<= 1) {
    float other[KSEL];
#pragma unroll
    for (int j = 0; j < KSEL; ++j) other[j] = __shfl_xor(lst[j], s);
#pragma unroll
    for (int j = 0; j < KSEL; ++j) bins11(other[j], lst);
  }

  if (quad == 0) {   // one writer per row: cand layout [row][part][k], sorted
    float* dst = cand + (size_t)row * (PPART * KSEL) + blockIdx.x * KSEL;
#pragma unroll
    for (int i = 0; i < KSEL; ++i) dst[i] = lst[i];
  }
}

// ---------------- merge: wave per row, 704 = 64 lanes x 11 ----------------
__global__ __launch_bounds__(256) void k_merge(const float* __restrict__ cand,
                                               float* __restrict__ out) {
  int w = threadIdx.x >> 6, lane = threadIdx.x & 63;
  int row = blockIdx.x * 4 + w;
  const float* src = cand + (size_t)row * (PPART * KSEL) + lane * KSEL;
  float lst[KSEL];
#pragma unroll
  for (int i = 0; i < KSEL; ++i) lst[i] = src[i];
#pragma unroll
  for (int s = 1; s <= 32; s <<= 1) {
    float other[KSEL];
#pragma unroll
    for (int j = 0; j < KSEL; ++j) other[j] = __shfl_xor(lst[j], s);
#pragma unroll
    for (int j = 0; j < KSEL; ++j) bins11(other[j], lst);
  }
  if (lane == 0) {
    // lst sorted ascending: lst[0] is the self-match -> dropped
    float s = 0.0f;
#pragma unroll
    for (int j = 1; j < KSEL; ++j) s += sqrtf(fmaxf(lst[j], 0.0f));
    out[row] = log1pf(s * 0.1f);      // mean over k=10, log1p
  }
}

extern "C" void kernel_launch(void* const* d_in, const int* in_sizes, int n_in,
                              void* d_out, int out_size, void* d_ws, size_t ws_size,
                              hipStream_t stream) {
  (void)in_sizes; (void)n_in; (void)out_size; (void)ws_size;
  const float* x   = (const float*)d_in[0];   // 2048 x 64
  const float* buf = (const float*)d_in[1];   // 131072 x 64
  float* out = (float*)d_out;

  char* ws = (char*)d_ws;
  _Float16* B16 = (_Float16*)ws;                       // 16,777,216 B
  float* bnorm  = (float*)(ws + 16777216);             //    524,288 B
  float* cand   = (float*)(ws + 17301504);             //  5,767,168 B

  k_prep_b<<<dim3(2048), dim3(256), 0, stream>>>(buf, B16, bnorm);
  k_main<<<dim3(PPART, NR / ROWS_PER_BLOCK), dim3(256), 0, stream>>>(x, B16, bnorm, cand);
  k_merge<<<dim3(NR / 4), dim3(256), 0, stream>>>(cand, out);
}

// Round 11
// 246.776 us; speedup vs baseline: 1.0806x; 1.0806x over previous
//
#include <hip/hip_runtime.h>
#include <math.h>

// Problem constants (fixed by reference)
#define NR 2048
#define MC 131072
#define DIM 64
#define KSEL 11                    // k+1 smallest kept per row
#define PPART 64                   // column partitions
#define PART_COLS (MC / PPART)     // 2048 cols per partition
#define CHUNK 128                  // cols per LDS chunk
#define NCHUNK (PART_COLS / CHUNK) // 16
#define ROWS_PER_BLOCK 64          // 4 waves x 16 rows
#define QDW 21                     // queue stride in dwords (odd -> all 32 banks)
#define QCAPP 20                   // pair capacity: TRIG + 16 (max pairs/chunk)
#define TRIG 4                     // drain when wave-max pair count exceeds this
#define BSTRIDE 68                 // f16 col stride in LDS: 34 dwords -> 2-way banks (free)

typedef _Float16 v8h __attribute__((ext_vector_type(8)));
typedef _Float16 v4h __attribute__((ext_vector_type(4)));
typedef _Float16 v2h __attribute__((ext_vector_type(2)));
typedef float v4f __attribute__((ext_vector_type(4)));

// ---------------- prep: bnorm (fp32) + buf -> f16 ----------------
__global__ __launch_bounds__(256) void k_prep_b(const float* __restrict__ buf,
                                                _Float16* __restrict__ B16,
                                                float* __restrict__ bnorm) {
  int gid = blockIdx.x * 256 + threadIdx.x;   // 4 threads per buffer row
  int row = gid >> 2, q = gid & 3;
  const float4* src = (const float4*)(buf + (size_t)row * DIM + q * 16);
  float4 f0 = src[0], f1 = src[1], f2 = src[2], f3 = src[3];
  float s = f0.x*f0.x + f0.y*f0.y + f0.z*f0.z + f0.w*f0.w
          + f1.x*f1.x + f1.y*f1.y + f1.z*f1.z + f1.w*f1.w
          + f2.x*f2.x + f2.y*f2.y + f2.z*f2.z + f2.w*f2.w
          + f3.x*f3.x + f3.y*f3.y + f3.z*f3.z + f3.w*f3.w;
  s += __shfl_xor(s, 1);
  s += __shfl_xor(s, 2);
  if (q == 0) bnorm[row] = s;
  union { _Float16 h[16]; uint4 u[2]; } o;
  o.h[0]=(_Float16)f0.x; o.h[1]=(_Float16)f0.y; o.h[2]=(_Float16)f0.z; o.h[3]=(_Float16)f0.w;
  o.h[4]=(_Float16)f1.x; o.h[5]=(_Float16)f1.y; o.h[6]=(_Float16)f1.z; o.h[7]=(_Float16)f1.w;
  o.h[8]=(_Float16)f2.x; o.h[9]=(_Float16)f2.y; o.h[10]=(_Float16)f2.z; o.h[11]=(_Float16)f2.w;
  o.h[12]=(_Float16)f3.x; o.h[13]=(_Float16)f3.y; o.h[14]=(_Float16)f3.z; o.h[15]=(_Float16)f3.w;
  uint4* dst = (uint4*)(B16 + (size_t)row * DIM + q * 16);
  dst[0] = o.u[0]; dst[1] = o.u[1];
}

// branchless bubble-insert into sorted-ascending 11-list. Inserting any value
// >= lst[10] (incl. +inf) is a no-op (it bubbles off the end). 22 min/max ops.
__device__ __forceinline__ void bins11(float v, float lst[KSEL]) {
  float t = v;
#pragma unroll
  for (int j = 0; j < KSEL; ++j) {
    float a = fminf(lst[j], t);
    t = fmaxf(lst[j], t);
    lst[j] = a;
  }
}

// ---------------- main: MFMA + deferred-drain pair queue + sorted top-11 -----
// D = A(bufcols) x B(xrows): C-layout gives each lane ONE x-row (n = lane&15).
// Scan packs (t0,t1) via cvt_pkrtz into one b32 queue slot per 2 candidates;
// the cursor advances on pair-pass (min < thrx). Drain runs ONLY when
// wave-max qo > TRIG or at the last chunk -- threshold staleness adds pushes
// but never drops a true top-11 member. Cap 20 pairs: 4 + 16/chunk max.
__global__ __launch_bounds__(256) void k_main(const float* __restrict__ x,
                                              const _Float16* __restrict__ B16,
                                              const float* __restrict__ bnorm,
                                              float* __restrict__ cand) {
  __shared__ __align__(16) _Float16 Bs[CHUNK * BSTRIDE];   // 17408 B
  __shared__ float bns[CHUNK];                             //   512 B
  __shared__ unsigned qmem[4][64 * QDW];                   // 21504 B -> 39424 B

  const int tid = threadIdx.x;
  const int w = tid >> 6, lane = tid & 63;
  const int quad = lane >> 4, l15 = lane & 15;
  const int row = blockIdx.y * ROWS_PER_BLOCK + w * 16 + l15;  // this lane's x-row
  const int pbase = blockIdx.x * PART_COLS;
  unsigned* q2 = &qmem[w][lane * QDW];

  // x fragments (B-operand: B[k = quad*8+j + 32ks][n = l15]) + exact fp32 norm
  v8h bx0, bx1;
  float xn;
  {
    const float* xr = x + (size_t)row * DIM;
    const float4* xp0 = (const float4*)(xr + quad * 8);
    float4 a0 = xp0[0], a1 = xp0[1];
    const float4* xp1 = (const float4*)(xr + 32 + quad * 8);
    float4 c0 = xp1[0], c1 = xp1[1];
    v8h h0, h1;
    h0[0]=(_Float16)a0.x; h0[1]=(_Float16)a0.y; h0[2]=(_Float16)a0.z; h0[3]=(_Float16)a0.w;
    h0[4]=(_Float16)a1.x; h0[5]=(_Float16)a1.y; h0[6]=(_Float16)a1.z; h0[7]=(_Float16)a1.w;
    h1[0]=(_Float16)c0.x; h1[1]=(_Float16)c0.y; h1[2]=(_Float16)c0.z; h1[3]=(_Float16)c0.w;
    h1[4]=(_Float16)c1.x; h1[5]=(_Float16)c1.y; h1[6]=(_Float16)c1.z; h1[7]=(_Float16)c1.w;
    bx0 = h0; bx1 = h1;
    float s = a0.x*a0.x + a0.y*a0.y + a0.z*a0.z + a0.w*a0.w
            + a1.x*a1.x + a1.y*a1.y + a1.z*a1.z + a1.w*a1.w
            + c0.x*c0.x + c0.y*c0.y + c0.z*c0.z + c0.w*c0.w
            + c1.x*c1.x + c1.y*c1.y + c1.z*c1.z + c1.w*c1.w;
    s += __shfl_xor(s, 16);   // each quad holds a disjoint 16 of the 64 k's
    s += __shfl_xor(s, 32);
    xn = s;
  }

  float lst[KSEL];   // sorted ascending; lst[10] = private threshold (d2 space)
#pragma unroll
  for (int i = 0; i < KSEL; ++i) lst[i] = __builtin_inff();
  float thrx = __builtin_inff();   // t-space: pass <=> t < thrx = thr - xn
  int qo = 0;                      // queue pair cursor (persists across chunks)

  // staging-prefetch registers (chunk c+1 loaded during chunk c's compute)
  const int scol = tid >> 1, shf = tid & 1;   // 2 threads/col, 32 f16 each
  union Stage { uint4 v4[4]; unsigned long long d[8]; } st;
  float pbn;
  {
    const uint4* src = (const uint4*)(B16 + (size_t)(pbase + scol) * DIM + shf * 32);
    st.v4[0] = src[0]; st.v4[1] = src[1]; st.v4[2] = src[2]; st.v4[3] = src[3];
    pbn = bnorm[pbase + (tid & (CHUNK - 1))];
  }

  for (int c = 0; c < NCHUNK; ++c) {
    const int cb = pbase + c * CHUNK;
    __syncthreads();   // Bs free (all waves done with previous chunk's reads)
    {
      // 8B-aligned b64 writes (BSTRIDE=68 -> byte stride 136, 8B-aligned)
      unsigned long long* dst8 = (unsigned long long*)(Bs + scol * BSTRIDE + shf * 32);
#pragma unroll
      for (int j = 0; j < 8; ++j) dst8[j] = st.d[j];
      if (tid < CHUNK) bns[tid] = pbn;
    }
    __syncthreads();   // staged

    // issue next chunk's loads now; latency hides behind scan+drain below
    if (c + 1 < NCHUNK) {
      const int nb = cb + CHUNK;
      const uint4* src = (const uint4*)(B16 + (size_t)(nb + scol) * DIM + shf * 32);
      st.v4[0] = src[0]; st.v4[1] = src[1]; st.v4[2] = src[2]; st.v4[3] = src[3];
      pbn = bnorm[nb + (tid & (CHUNK - 1))];
    }

#pragma unroll
    for (int mt = 0; mt < 8; ++mt) {
      const _Float16* bp = Bs + (mt * 16 + l15) * BSTRIDE + quad * 8;
      v4h lo0 = *(const v4h*)bp;          // 8B-aligned ds_read_b64 pairs
      v4h hi0 = *(const v4h*)(bp + 4);
      v4h lo1 = *(const v4h*)(bp + 32);
      v4h hi1 = *(const v4h*)(bp + 36);
      v8h a0 = __builtin_shufflevector(lo0, hi0, 0, 1, 2, 3, 4, 5, 6, 7);
      v8h a1 = __builtin_shufflevector(lo1, hi1, 0, 1, 2, 3, 4, 5, 6, 7);
      v4f acc = (v4f)(0.0f);
      acc = __builtin_amdgcn_mfma_f32_16x16x32_f16(a0, bx0, acc, 0, 0, 0);
      acc = __builtin_amdgcn_mfma_f32_16x16x32_f16(a1, bx1, acc, 0, 0, 0);
      float4 bn4 = *(const float4*)&bns[mt * 16 + quad * 4];
      float t0 = fmaf(acc[0], -2.0f, bn4.x);   // d2 = t + xn
      float t1 = fmaf(acc[1], -2.0f, bn4.y);
      float t2 = fmaf(acc[2], -2.0f, bn4.z);
      float t3 = fmaf(acc[3], -2.0f, bn4.w);
      // pair-packed pushes: one b32 slot per 2 candidates, advance on pass.
      // The non-passing half of a pushed pair is a genuine d2 -> safe insert.
      unsigned pk0 = __builtin_bit_cast(unsigned, __builtin_amdgcn_cvt_pkrtz(t0, t1));
      unsigned pk1 = __builtin_bit_cast(unsigned, __builtin_amdgcn_cvt_pkrtz(t2, t3));
      q2[qo] = pk0;
      qo += (fminf(t0, t1) < thrx) ? 1 : 0;
      q2[qo] = pk1;
      qo += (fminf(t2, t3) < thrx) ? 1 : 0;
    }

    // deferred drain: only when some lane's queue is filling, or at the end
    if (__ballot(qo > TRIG) || c == NCHUNK - 1) {
      for (int i = 0; __ballot(i < qo); ++i) {
        v2h p = __builtin_bit_cast(v2h, q2[i]);
        bool ok = i < qo;
        float v0 = (float)p[0] + xn;
        float v1 = (float)p[1] + xn;
        v0 = ok ? v0 : __builtin_inff();   // guard stale slots (already drained)
        v1 = ok ? v1 : __builtin_inff();
        float m = fminf(v0, v1);
        if (__ballot(m < lst[KSEL - 1])) {  // any lane improves its list?
          bins11(v0, lst);                  // v >= lst[10] inserts are no-ops
          bins11(v1, lst);
        }
      }
      qo = 0;
      // tighten shared threshold: min over the 4 quads holding this row
      float th = fminf(lst[KSEL - 1], __shfl_xor(lst[KSEL - 1], 16));
      th = fminf(th, __shfl_xor(th, 32));
      thrx = th - xn;
    }
  }

  // merge the 4 quads' sorted lists (disjoint col subsets of the same row)
#pragma unroll
  for (int s = 16; s <= 32; s <<= 1) {
    float other[KSEL];
#pragma unroll
    for (int j = 0; j < KSEL; ++j) other[j] = __shfl_xor(lst[j], s);
#pragma unroll
    for (int j = 0; j < KSEL; ++j) bins11(other[j], lst);
  }

  if (quad == 0) {   // one writer per row: cand layout [row][part][k], sorted
    float* dst = cand + (size_t)row * (PPART * KSEL) + blockIdx.x * KSEL;
#pragma unroll
    for (int i = 0; i < KSEL; ++i) dst[i] = lst[i];
  }
}

// ---------------- merge: wave per row, 704 = 64 lanes x 11 ----------------
__global__ __launch_bounds__(256) void k_merge(const float* __restrict__ cand,
                                               float* __restrict__ out) {
  int w = threadIdx.x >> 6, lane = threadIdx.x & 63;
  int row = blockIdx.x * 4 + w;
  const float* src = cand + (size_t)row * (PPART * KSEL) + lane * KSEL;
  float lst[KSEL];
#pragma unroll
  for (int i = 0; i < KSEL; ++i) lst[i] = src[i];
#pragma unroll
  for (int s = 1; s <= 32; s <<= 1) {
    float other[KSEL];
#pragma unroll
    for (int j = 0; j < KSEL; ++j) other[j] = __shfl_xor(lst[j], s);
#pragma unroll
    for (int j = 0; j < KSEL; ++j) bins11(other[j], lst);
  }
  if (lane == 0) {
    // lst sorted ascending: lst[0] is the self-match -> dropped
    float s = 0.0f;
#pragma unroll
    for (int j = 1; j < KSEL; ++j) s += sqrtf(fmaxf(lst[j], 0.0f));
    out[row] = log1pf(s * 0.1f);      // mean over k=10, log1p
  }
}

extern "C" void kernel_launch(void* const* d_in, const int* in_sizes, int n_in,
                              void* d_out, int out_size, void* d_ws, size_t ws_size,
                              hipStream_t stream) {
  (void)in_sizes; (void)n_in; (void)out_size; (void)ws_size;
  const float* x   = (const float*)d_in[0];   // 2048 x 64
  const float* buf = (const float*)d_in[1];   // 131072 x 64
  float* out = (float*)d_out;

  char* ws = (char*)d_ws;
  _Float16* B16 = (_Float16*)ws;                       // 16,777,216 B
  float* bnorm  = (float*)(ws + 16777216);             //    524,288 B
  float* cand   = (float*)(ws + 17301504);             //  5,767,168 B

  k_prep_b<<<dim3(2048), dim3(256), 0, stream>>>(buf, B16, bnorm);
  k_main<<<dim3(PPART, NR / ROWS_PER_BLOCK), dim3(256), 0, stream>>>(x, B16, bnorm, cand);
  k_merge<<<dim3(NR / 4), dim3(256), 0, stream>>>(cand, out);
}

// Round 12
// 230.324 us; speedup vs baseline: 1.1578x; 1.0714x over previous
//
#include <hip/hip_runtime.h>
#include <math.h>

// Problem constants (fixed by reference)
#define NR 2048
#define MC 131072
#define DIM 64
#define KSEL 11                    // k+1 smallest kept per row
#define PPART 64                   // column partitions
#define PART_COLS (MC / PPART)     // 2048 cols per partition
#define CHUNK 128                  // cols per LDS chunk
#define NCHUNK (PART_COLS / CHUNK) // 16
#define ROWS_PER_BLOCK 64          // 4 waves x 16 rows
#define QDW 13                     // queue stride in dwords (odd -> all 32 banks)
#define QCAP 26                    // f16 slots per lane (= 2*QDW)
#define BSTRIDE 68                 // f16 col stride in LDS: 34 dwords -> 2-way banks (free)

typedef _Float16 v8h __attribute__((ext_vector_type(8)));
typedef _Float16 v4h __attribute__((ext_vector_type(4)));
typedef _Float16 v2h __attribute__((ext_vector_type(2)));
typedef float v4f __attribute__((ext_vector_type(4)));

// ---------------- prep: bnorm (fp32) + buf -> f16 ----------------
__global__ __launch_bounds__(256) void k_prep_b(const float* __restrict__ buf,
                                                _Float16* __restrict__ B16,
                                                float* __restrict__ bnorm) {
  int gid = blockIdx.x * 256 + threadIdx.x;   // 4 threads per buffer row
  int row = gid >> 2, q = gid & 3;
  const float4* src = (const float4*)(buf + (size_t)row * DIM + q * 16);
  float4 f0 = src[0], f1 = src[1], f2 = src[2], f3 = src[3];
  float s = f0.x*f0.x + f0.y*f0.y + f0.z*f0.z + f0.w*f0.w
          + f1.x*f1.x + f1.y*f1.y + f1.z*f1.z + f1.w*f1.w
          + f2.x*f2.x + f2.y*f2.y + f2.z*f2.z + f2.w*f2.w
          + f3.x*f3.x + f3.y*f3.y + f3.z*f3.z + f3.w*f3.w;
  s += __shfl_xor(s, 1);
  s += __shfl_xor(s, 2);
  if (q == 0) bnorm[row] = s;
  union { _Float16 h[16]; uint4 u[2]; } o;
  o.h[0]=(_Float16)f0.x; o.h[1]=(_Float16)f0.y; o.h[2]=(_Float16)f0.z; o.h[3]=(_Float16)f0.w;
  o.h[4]=(_Float16)f1.x; o.h[5]=(_Float16)f1.y; o.h[6]=(_Float16)f1.z; o.h[7]=(_Float16)f1.w;
  o.h[8]=(_Float16)f2.x; o.h[9]=(_Float16)f2.y; o.h[10]=(_Float16)f2.z; o.h[11]=(_Float16)f2.w;
  o.h[12]=(_Float16)f3.x; o.h[13]=(_Float16)f3.y; o.h[14]=(_Float16)f3.z; o.h[15]=(_Float16)f3.w;
  uint4* dst = (uint4*)(B16 + (size_t)row * DIM + q * 16);
  dst[0] = o.u[0]; dst[1] = o.u[1];
}

// branchless bubble-insert into sorted-ascending 11-list. Inserting any value
// >= lst[10] (incl. +inf) is a no-op (it bubbles off the end). 22 min/max ops.
__device__ __forceinline__ void bins11(float v, float lst[KSEL]) {
  float t = v;
#pragma unroll
  for (int j = 0; j < KSEL; ++j) {
    float a = fminf(lst[j], t);
    t = fmaxf(lst[j], t);
    lst[j] = a;
  }
}

// ---------------- main: MFMA + f16 queue + sorted top-11 ---------------------
// D = A(bufcols) x B(xrows): C-layout gives each lane ONE x-row (n = lane&15).
// Chunk 0 (thr = +inf, every candidate passes) inserts directly -- no queue,
// no ballots. Chunks 1+ push f16 t = bn - 2*dot into a lane-private queue
// (13-dword stride, conflict-free) against the row-shared threshold, drained
// every chunk with 4-wide ballot-gated batches. 31,232 B LDS -> 5 blocks/CU.
__global__ __launch_bounds__(256, 5) void k_main(const float* __restrict__ x,
                                                 const _Float16* __restrict__ B16,
                                                 const float* __restrict__ bnorm,
                                                 float* __restrict__ cand) {
  __shared__ __align__(16) _Float16 Bs[CHUNK * BSTRIDE];   // 17408 B
  __shared__ float bns[CHUNK];                             //   512 B
  __shared__ unsigned qmem[4][64 * QDW];                   // 13312 B -> 31232 B

  const int tid = threadIdx.x;
  const int w = tid >> 6, lane = tid & 63;
  const int quad = lane >> 4, l15 = lane & 15;
  const int row = blockIdx.y * ROWS_PER_BLOCK + w * 16 + l15;  // this lane's x-row
  const int pbase = blockIdx.x * PART_COLS;
  unsigned* q2 = &qmem[w][lane * QDW];          // dword view
  _Float16* qh = (_Float16*)q2;                 // f16 view

  // x fragments (B-operand: B[k = quad*8+j + 32ks][n = l15]) + exact fp32 norm
  v8h bx0, bx1;
  float xn;
  {
    const float* xr = x + (size_t)row * DIM;
    const float4* xp0 = (const float4*)(xr + quad * 8);
    float4 a0 = xp0[0], a1 = xp0[1];
    const float4* xp1 = (const float4*)(xr + 32 + quad * 8);
    float4 c0 = xp1[0], c1 = xp1[1];
    v8h h0, h1;
    h0[0]=(_Float16)a0.x; h0[1]=(_Float16)a0.y; h0[2]=(_Float16)a0.z; h0[3]=(_Float16)a0.w;
    h0[4]=(_Float16)a1.x; h0[5]=(_Float16)a1.y; h0[6]=(_Float16)a1.z; h0[7]=(_Float16)a1.w;
    h1[0]=(_Float16)c0.x; h1[1]=(_Float16)c0.y; h1[2]=(_Float16)c0.z; h1[3]=(_Float16)c0.w;
    h1[4]=(_Float16)c1.x; h1[5]=(_Float16)c1.y; h1[6]=(_Float16)c1.z; h1[7]=(_Float16)c1.w;
    bx0 = h0; bx1 = h1;
    float s = a0.x*a0.x + a0.y*a0.y + a0.z*a0.z + a0.w*a0.w
            + a1.x*a1.x + a1.y*a1.y + a1.z*a1.z + a1.w*a1.w
            + c0.x*c0.x + c0.y*c0.y + c0.z*c0.z + c0.w*c0.w
            + c1.x*c1.x + c1.y*c1.y + c1.z*c1.z + c1.w*c1.w;
    s += __shfl_xor(s, 16);   // each quad holds a disjoint 16 of the 64 k's
    s += __shfl_xor(s, 32);
    xn = s;
  }

  float lst[KSEL];   // sorted ascending; lst[10] = private threshold (d2 space)
#pragma unroll
  for (int i = 0; i < KSEL; ++i) lst[i] = __builtin_inff();
  float thrx = __builtin_inff();   // t-space: pass <=> t < thrx = thr - xn
  int qo = 0;                      // queue write cursor (f16 elements)

  // drain the queue (4 values per iteration) + tighten the shared threshold
  auto drain = [&]() {
    for (int i = 0; __ballot(i < qo); i += 4) {
      unsigned ua = q2[i >> 1], ub = q2[(i >> 1) + 1];
      v2h pa = __builtin_bit_cast(v2h, ua);
      v2h pb = __builtin_bit_cast(v2h, ub);
      float v0 = (float)pa[0] + xn, v1 = (float)pa[1] + xn;
      float v2 = (float)pb[0] + xn, v3 = (float)pb[1] + xn;
      v0 = (i + 0 < qo) ? v0 : __builtin_inff();
      v1 = (i + 1 < qo) ? v1 : __builtin_inff();
      v2 = (i + 2 < qo) ? v2 : __builtin_inff();
      v3 = (i + 3 < qo) ? v3 : __builtin_inff();
      float m = fminf(fminf(v0, v1), fminf(v2, v3));
      if (__ballot(m < lst[KSEL - 1])) {   // any lane improves its list?
        bins11(v0, lst); bins11(v1, lst);  // v >= lst[10] inserts are no-ops
        bins11(v2, lst); bins11(v3, lst);
      }
    }
    qo = 0;
    float th = fminf(lst[KSEL - 1], __shfl_xor(lst[KSEL - 1], 16));
    th = fminf(th, __shfl_xor(th, 32));
    thrx = th - xn;
  };

  // staging-prefetch registers (chunk c+1 loaded during chunk c's compute)
  const int scol = tid >> 1, shf = tid & 1;   // 2 threads/col, 32 f16 each
  union Stage { uint4 v4[4]; unsigned long long d[8]; } st;
  float pbn;
  {
    const uint4* src = (const uint4*)(B16 + (size_t)(pbase + scol) * DIM + shf * 32);
    st.v4[0] = src[0]; st.v4[1] = src[1]; st.v4[2] = src[2]; st.v4[3] = src[3];
    pbn = bnorm[pbase + (tid & (CHUNK - 1))];
  }

  for (int c = 0; c < NCHUNK; ++c) {
    const int cb = pbase + c * CHUNK;
    __syncthreads();   // Bs free (all waves done with previous chunk's reads)
    {
      // 8B-aligned b64 writes (BSTRIDE=68 -> byte stride 136, 8B-aligned)
      unsigned long long* dst8 = (unsigned long long*)(Bs + scol * BSTRIDE + shf * 32);
#pragma unroll
      for (int j = 0; j < 8; ++j) dst8[j] = st.d[j];
      if (tid < CHUNK) bns[tid] = pbn;
    }
    __syncthreads();   // staged

    // issue next chunk's loads now; latency hides behind scan+drain below
    if (c + 1 < NCHUNK) {
      const int nb = cb + CHUNK;
      const uint4* src = (const uint4*)(B16 + (size_t)(nb + scol) * DIM + shf * 32);
      st.v4[0] = src[0]; st.v4[1] = src[1]; st.v4[2] = src[2]; st.v4[3] = src[3];
      pbn = bnorm[nb + (tid & (CHUNK - 1))];
    }

    if (c == 0) {
      // warm-up: threshold is +inf, every candidate would pass -- insert
      // directly (no queue, no ballots), then establish the threshold.
#pragma unroll
      for (int mt = 0; mt < 8; ++mt) {
        const _Float16* bp = Bs + (mt * 16 + l15) * BSTRIDE + quad * 8;
        v4h lo0 = *(const v4h*)bp;
        v4h hi0 = *(const v4h*)(bp + 4);
        v4h lo1 = *(const v4h*)(bp + 32);
        v4h hi1 = *(const v4h*)(bp + 36);
        v8h a0 = __builtin_shufflevector(lo0, hi0, 0, 1, 2, 3, 4, 5, 6, 7);
        v8h a1 = __builtin_shufflevector(lo1, hi1, 0, 1, 2, 3, 4, 5, 6, 7);
        v4f acc = (v4f)(0.0f);
        acc = __builtin_amdgcn_mfma_f32_16x16x32_f16(a0, bx0, acc, 0, 0, 0);
        acc = __builtin_amdgcn_mfma_f32_16x16x32_f16(a1, bx1, acc, 0, 0, 0);
        float4 bn4 = *(const float4*)&bns[mt * 16 + quad * 4];
        bins11(fmaf(acc[0], -2.0f, bn4.x + xn), lst);
        bins11(fmaf(acc[1], -2.0f, bn4.y + xn), lst);
        bins11(fmaf(acc[2], -2.0f, bn4.z + xn), lst);
        bins11(fmaf(acc[3], -2.0f, bn4.w + xn), lst);
      }
      float th = fminf(lst[KSEL - 1], __shfl_xor(lst[KSEL - 1], 16));
      th = fminf(th, __shfl_xor(th, 32));
      thrx = th - xn;
    } else {
#pragma unroll
      for (int mt = 0; mt < 8; ++mt) {
        // insurance: guarantee room for this mt's <=4 pushes (post-warm-up
        // the wave-max cursor stays far below QCAP; this never fires)
        if (__ballot(qo > QCAP - 4)) drain();
        const _Float16* bp = Bs + (mt * 16 + l15) * BSTRIDE + quad * 8;
        v4h lo0 = *(const v4h*)bp;
        v4h hi0 = *(const v4h*)(bp + 4);
        v4h lo1 = *(const v4h*)(bp + 32);
        v4h hi1 = *(const v4h*)(bp + 36);
        v8h a0 = __builtin_shufflevector(lo0, hi0, 0, 1, 2, 3, 4, 5, 6, 7);
        v8h a1 = __builtin_shufflevector(lo1, hi1, 0, 1, 2, 3, 4, 5, 6, 7);
        v4f acc = (v4f)(0.0f);
        acc = __builtin_amdgcn_mfma_f32_16x16x32_f16(a0, bx0, acc, 0, 0, 0);
        acc = __builtin_amdgcn_mfma_f32_16x16x32_f16(a1, bx1, acc, 0, 0, 0);
        float4 bn4 = *(const float4*)&bns[mt * 16 + quad * 4];
        float t0 = fmaf(acc[0], -2.0f, bn4.x);   // d2 = t + xn
        float t1 = fmaf(acc[1], -2.0f, bn4.y);
        float t2 = fmaf(acc[2], -2.0f, bn4.z);
        float t3 = fmaf(acc[3], -2.0f, bn4.w);
        // branchless pushes: always write; advance only on pass
        qh[qo] = (_Float16)t0; qo += (t0 < thrx) ? 1 : 0;
        qh[qo] = (_Float16)t1; qo += (t1 < thrx) ? 1 : 0;
        qh[qo] = (_Float16)t2; qo += (t2 < thrx) ? 1 : 0;
        qh[qo] = (_Float16)t3; qo += (t3 < thrx) ? 1 : 0;
      }
      if (__ballot(qo > 0)) drain();
    }
  }

  // merge the 4 quads' sorted lists (disjoint col subsets of the same row)
#pragma unroll
  for (int s = 16; s <= 32; s <<= 1) {
    float other[KSEL];
#pragma unroll
    for (int j = 0; j < KSEL; ++j) other[j] = __shfl_xor(lst[j], s);
#pragma unroll
    for (int j = 0; j < KSEL; ++j) bins11(other[j], lst);
  }

  if (quad == 0) {   // one writer per row: cand layout [row][part][k], sorted
    float* dst = cand + (size_t)row * (PPART * KSEL) + blockIdx.x * KSEL;
#pragma unroll
    for (int i = 0; i < KSEL; ++i) dst[i] = lst[i];
  }
}

// ---------------- merge: wave per row, 704 = 64 lanes x 11 ----------------
__global__ __launch_bounds__(256) void k_merge(const float* __restrict__ cand,
                                               float* __restrict__ out) {
  int w = threadIdx.x >> 6, lane = threadIdx.x & 63;
  int row = blockIdx.x * 4 + w;
  const float* src = cand + (size_t)row * (PPART * KSEL) + lane * KSEL;
  float lst[KSEL];
#pragma unroll
  for (int i = 0; i < KSEL; ++i) lst[i] = src[i];
#pragma unroll
  for (int s = 1; s <= 32; s <<= 1) {
    float other[KSEL];
#pragma unroll
    for (int j = 0; j < KSEL; ++j) other[j] = __shfl_xor(lst[j], s);
#pragma unroll
    for (int j = 0; j < KSEL; ++j) bins11(other[j], lst);
  }
  if (lane == 0) {
    // lst sorted ascending: lst[0] is the self-match -> dropped
    float s = 0.0f;
#pragma unroll
    for (int j = 1; j < KSEL; ++j) s += sqrtf(fmaxf(lst[j], 0.0f));
    out[row] = log1pf(s * 0.1f);      // mean over k=10, log1p
  }
}

extern "C" void kernel_launch(void* const* d_in, const int* in_sizes, int n_in,
                              void* d_out, int out_size, void* d_ws, size_t ws_size,
                              hipStream_t stream) {
  (void)in_sizes; (void)n_in; (void)out_size; (void)ws_size;
  const float* x   = (const float*)d_in[0];   // 2048 x 64
  const float* buf = (const float*)d_in[1];   // 131072 x 64
  float* out = (float*)d_out;

  char* ws = (char*)d_ws;
  _Float16* B16 = (_Float16*)ws;                       // 16,777,216 B
  float* bnorm  = (float*)(ws + 16777216);             //    524,288 B
  float* cand   = (float*)(ws + 17301504);             //  5,767,168 B

  k_prep_b<<<dim3(2048), dim3(256), 0, stream>>>(buf, B16, bnorm);
  k_main<<<dim3(PPART, NR / ROWS_PER_BLOCK), dim3(256), 0, stream>>>(x, B16, bnorm, cand);
  k_merge<<<dim3(NR / 4), dim3(256), 0, stream>>>(cand, out);
}